// Round 3
// baseline (275.142 us; speedup 1.0000x reference)
//
#include <hip/hip_runtime.h>

#define MB    32        // B*T slices
#define CCH   256       // channels C
#define QCH   32        // q/k channels
#define NPIX  1024      // W*H
#define SLICE (CCH * NPIX)   // 262144
#define L2E   1.44269504088896340736f
#define SHIFT 32.0f     // fixed softmax shift (energies |e|<~60 in log2 domain; fp32 range +-126)

typedef __bf16          bf16x8 __attribute__((ext_vector_type(8)));
typedef float           f32x4  __attribute__((ext_vector_type(4)));
typedef unsigned int    u32x4  __attribute__((ext_vector_type(4)));
typedef unsigned short  u16x4  __attribute__((ext_vector_type(4)));

__device__ __forceinline__ unsigned short f2bf(float f) {
    unsigned int u = __builtin_bit_cast(unsigned int, f);
    u += 0x7FFFu + ((u >> 16) & 1u);          // RTNE (inputs well-behaved, no NaN)
    return (unsigned short)(u >> 16);
}
__device__ __forceinline__ bf16x8 ldfrag(const unsigned short* p) {
    u32x4 u = *(const u32x4*)p;
    return __builtin_bit_cast(bf16x8, u);
}

// workspace byte offsets
#define WB_OFF 0u                 // 320*256 bf16      = 163840 B
#define A2_OFF 163840u            // 32*1024 f32       = 131072 B
#define XT_OFF 294912u            // 32*1024*256 bf16  = 16777216 B
#define QT_OFF 17072128u          // 32*1024*32 bf16   = 2097152 B
#define KT_OFF 19169280u          // 32*1024*32 bf16   = 2097152 B
#define V_OFF  21266432u          // 32*256*1024 bf16  = 16777216 B -> end ~38 MB

// ---------------------------------------------------------------------------
// K0w: convert stacked [wq;wk;wv] (320x256 f32) -> Wb bf16
// ---------------------------------------------------------------------------
__global__ __launch_bounds__(256) void k_prep_w(
    const float* __restrict__ wq, const float* __restrict__ wk,
    const float* __restrict__ wv, unsigned short* __restrict__ Wb)
{
    int i4 = (blockIdx.x * 256 + threadIdx.x) * 4;   // 80 blocks cover 81920
    int o = i4 >> 8, c = i4 & 255;
    const float* src = (o < 32) ? wq + (size_t)o * CCH + c
                     : (o < 64) ? wk + (size_t)(o - 32) * CCH + c
                                : wv + (size_t)(o - 64) * CCH + c;
    float4 v = *(const float4*)src;
    u16x4 d = { f2bf(v.x), f2bf(v.y), f2bf(v.z), f2bf(v.w) };
    *(u16x4*)(Wb + i4) = d;
}

// ---------------------------------------------------------------------------
// K0x: transpose-convert x (f32 [c][n] per slice) -> Xt bf16 [n][c]
// ---------------------------------------------------------------------------
__global__ __launch_bounds__(256) void k_prep_x(
    const float* __restrict__ x, unsigned short* __restrict__ Xt)
{
    __shared__ unsigned short Ts[64][72];
    const int t = threadIdx.x;
    const int n0 = blockIdx.x * 64, c0 = blockIdx.y * 64, mi = blockIdx.z;
    const float* xp = x + (size_t)mi * SLICE;
    unsigned short* Xp = Xt + (size_t)mi * SLICE;
#pragma unroll
    for (int r = 0; r < 4; ++r) {
        int cl = (t >> 4) + r * 16;
        int nl = (t & 15) * 4;
        float4 v = *(const float4*)(xp + (size_t)(c0 + cl) * NPIX + n0 + nl);
        Ts[nl + 0][cl] = f2bf(v.x); Ts[nl + 1][cl] = f2bf(v.y);
        Ts[nl + 2][cl] = f2bf(v.z); Ts[nl + 3][cl] = f2bf(v.w);
    }
    __syncthreads();
#pragma unroll
    for (int r = 0; r < 4; ++r) {
        int nl = (t >> 4) + r * 16;
        int cl = (t & 15) * 4;
        u16x4 d = *(const u16x4*)&Ts[nl][cl];
        *(u16x4*)(Xp + (size_t)(n0 + nl) * CCH + c0 + cl) = d;
    }
}

// ---------------------------------------------------------------------------
// K1: MFMA projections. O(320x1024) = Wb @ Xt^T per slice.
// Wave: o-tile 16 x n-tile 64 (4 sub-tiles). A=Wb rows, B=Xt rows.
// Epilogue: o<32 -> Qt[n][o] bf16 *L2E + bq; o<64 -> Kt[n][o] + bk;
//           else V in MFMA A-FRAGMENT layout Vf[c16][n5][lane][8] + bv.
// ---------------------------------------------------------------------------
__global__ __launch_bounds__(256) void k_proj(
    const unsigned short* __restrict__ Wb, const unsigned short* __restrict__ Xt,
    const float* __restrict__ bq, const float* __restrict__ bk,
    const float* __restrict__ bv,
    unsigned short* __restrict__ Qt, unsigned short* __restrict__ Kt,
    unsigned short* __restrict__ V)
{
    const int t = threadIdx.x, lane = t & 63, w = t >> 6;
    const int lj = lane & 15, q = lane >> 4;
    const int n0 = blockIdx.x * 64;
    const int o16 = blockIdx.y * 64 + w * 16;
    const int mi = blockIdx.z;
    const unsigned short* Xp = Xt + (size_t)mi * SLICE;

    f32x4 acc[4];
#pragma unroll
    for (int b = 0; b < 4; ++b) acc[b] = (f32x4){0.f, 0.f, 0.f, 0.f};

#pragma unroll
    for (int kc = 0; kc < CCH; kc += 32) {
        bf16x8 a = ldfrag(Wb + (size_t)(o16 + lj) * CCH + kc + q * 8);
#pragma unroll
        for (int b = 0; b < 4; ++b) {
            bf16x8 xb = ldfrag(Xp + (size_t)(n0 + b * 16 + lj) * CCH + kc + q * 8);
            acc[b] = __builtin_amdgcn_mfma_f32_16x16x32_bf16(a, xb, acc[b], 0, 0, 0);
        }
    }

    const int ob = o16 + 4 * q;        // this lane's 4 output rows: ob..ob+3
    if (o16 < 32) {                    // Q -> Qt[n][o], pre-scaled by log2(e)
        unsigned short* Qp = Qt + (size_t)mi * NPIX * QCH;
        float b0 = bq[ob], b1 = bq[ob + 1], b2 = bq[ob + 2], b3 = bq[ob + 3];
#pragma unroll
        for (int b = 0; b < 4; ++b) {
            int n = n0 + b * 16 + lj;
            u16x4 d = { f2bf((acc[b][0] + b0) * L2E), f2bf((acc[b][1] + b1) * L2E),
                        f2bf((acc[b][2] + b2) * L2E), f2bf((acc[b][3] + b3) * L2E) };
            *(u16x4*)(Qp + (size_t)n * QCH + ob) = d;
        }
    } else if (o16 < 64) {             // K -> Kt[n][o]
        unsigned short* Kp = Kt + (size_t)mi * NPIX * QCH;
        int o2 = ob - 32;
        float b0 = bk[o2], b1 = bk[o2 + 1], b2 = bk[o2 + 2], b3 = bk[o2 + 3];
#pragma unroll
        for (int b = 0; b < 4; ++b) {
            int n = n0 + b * 16 + lj;
            u16x4 d = { f2bf(acc[b][0] + b0), f2bf(acc[b][1] + b1),
                        f2bf(acc[b][2] + b2), f2bf(acc[b][3] + b3) };
            *(u16x4*)(Kp + (size_t)n * QCH + o2) = d;
        }
    } else {                           // V -> fragment layout
        unsigned short* Vw = V + (size_t)mi * SLICE;
        const int c16 = (o16 - 64) >> 4;   // c-tile index 0..15
        const int n05 = n0 >> 5;
        const int cb = (o16 - 64) + 4 * q;
        float bb[4] = { bv[cb], bv[cb + 1], bv[cb + 2], bv[cb + 3] };
        const int ni = lj & 7;
#pragma unroll
        for (int b = 0; b < 4; ++b) {
            int n5 = n05 + (b >> 1);
            int fl = ((2 * b + (lj >> 3)) & 3) * 16 + 4 * q;   // frag-lane base
            size_t base = ((size_t)(c16 * 32 + n5) * 64 + fl) * 8 + ni;
#pragma unroll
            for (int r = 0; r < 4; ++r)
                Vw[base + (size_t)r * 8] = f2bf(acc[b][r] + bb[r]);
        }
    }
}

// ---------------------------------------------------------------------------
// K2: softmax row sums with fixed shift (no online max -> no serial exp2
// chain). Same mfma tiles as K3 -> bitwise-consistent E. a2[n]=SHIFT+log2(S).
// ---------------------------------------------------------------------------
__global__ __launch_bounds__(256) void k_stats(
    const unsigned short* __restrict__ Qt, const unsigned short* __restrict__ Kt,
    float* __restrict__ a2f)
{
    const int t = threadIdx.x, lane = t & 63, w = t >> 6;
    const int lj = lane & 15, q = lane >> 4;
    const int n16 = blockIdx.x * 64 + w * 16;
    const int mi = blockIdx.y;
    const unsigned short* Qp = Qt + (size_t)mi * NPIX * QCH;
    const unsigned short* Kp = Kt + (size_t)mi * NPIX * QCH;

    bf16x8 qa = ldfrag(Qp + (size_t)(n16 + lj) * QCH + q * 8);

    float s[4] = { 0.f, 0.f, 0.f, 0.f };
#pragma unroll 8
    for (int jc = 0; jc < NPIX; jc += 16) {
        bf16x8 kb = ldfrag(Kp + (size_t)(jc + lj) * QCH + q * 8);
        f32x4 z = (f32x4){0.f, 0.f, 0.f, 0.f};
        f32x4 e = __builtin_amdgcn_mfma_f32_16x16x32_bf16(qa, kb, z, 0, 0, 0);
#pragma unroll
        for (int r = 0; r < 4; ++r) s[r] += exp2f(e[r] - SHIFT);
    }
#pragma unroll
    for (int msk = 1; msk <= 8; msk <<= 1)
#pragma unroll
        for (int r = 0; r < 4; ++r) s[r] += __shfl_xor(s[r], msk, 64);

    if (lj == 0) {
        float* apo = a2f + (size_t)mi * NPIX;
#pragma unroll
        for (int r = 0; r < 4; ++r)
            apo[n16 + 4 * q + r] = SHIFT + log2f(s[r]);
    }
}

// ---------------------------------------------------------------------------
// K3: fused second pass, barrier-free. Block = 4 waves x j16-tile, c-half
// split (128 ch). Per chunk: E (2 mfma, Qt/Kt coalesced rows) -> P ->
// wave-local LDS transpose -> 8 V.P mfma with V fragments loaded straight
// from global (coalesced 1KB per wave-load, L1/L2-served).
// ---------------------------------------------------------------------------
__global__ __launch_bounds__(256) void k_attn_out(
    const float* __restrict__ x, const float* __restrict__ gamma,
    const unsigned short* __restrict__ Qt, const unsigned short* __restrict__ Kt,
    const unsigned short* __restrict__ Vf, const float* __restrict__ a2f,
    float* __restrict__ out)
{
    __shared__ unsigned short Ps[4][16][40];    // per-wave P tile [j][n], 80 B rows

    const int t = threadIdx.x, lane = t & 63, w = t >> 6;
    const int lj = lane & 15, q = lane >> 4;
    const int j16 = blockIdx.x * 64 + w * 16;
    const int ch  = blockIdx.y;                 // channel half 0/1
    const int mi  = blockIdx.z;

    const unsigned short* Qp = Qt + (size_t)mi * NPIX * QCH;
    const unsigned short* Kp = Kt + (size_t)mi * NPIX * QCH;
    const unsigned short* Vp = Vf + (size_t)mi * SLICE + (size_t)ch * 8 * 16384;
    const float* ap = a2f + (size_t)mi * NPIX;

    bf16x8 kb = ldfrag(Kp + (size_t)(j16 + lj) * QCH + q * 8);   // fixed per wave

    f32x4 acc[8];
#pragma unroll
    for (int ct = 0; ct < 8; ++ct) acc[ct] = (f32x4){0.f, 0.f, 0.f, 0.f};

#pragma unroll 4
    for (int nc = 0; nc < NPIX; nc += 32) {
        // E phase: two 16x16 tiles -> P bf16 into wave-local Ps
#pragma unroll
        for (int sub = 0; sub < 2; ++sub) {
            int nr = nc + sub * 16;
            bf16x8 qa = ldfrag(Qp + (size_t)(nr + lj) * QCH + q * 8);
            f32x4 z = (f32x4){0.f, 0.f, 0.f, 0.f};
            f32x4 e = __builtin_amdgcn_mfma_f32_16x16x32_bf16(qa, kb, z, 0, 0, 0);
            f32x4 a4 = *(const f32x4*)(ap + nr + 4 * q);
            u16x4 pv = { f2bf(exp2f(e[0] - a4[0])), f2bf(exp2f(e[1] - a4[1])),
                         f2bf(exp2f(e[2] - a4[2])), f2bf(exp2f(e[3] - a4[3])) };
            *(u16x4*)&Ps[w][lj][sub * 16 + 4 * q] = pv;
        }
        bf16x8 pf = ldfrag(&Ps[w][lj][q * 8]);   // B operand: P[n=q*8+i][j=lj]

        // O accumulation: 8 c-tiles, V fragments direct from global
        const unsigned short* vb = Vp + ((size_t)(nc >> 5) * 64 + lane) * 8;
#pragma unroll
        for (int ct = 0; ct < 8; ++ct) {
            bf16x8 vf = ldfrag(vb + (size_t)ct * 16384);
            acc[ct] = __builtin_amdgcn_mfma_f32_16x16x32_bf16(vf, pf, acc[ct], 0, 0, 0);
        }
    }

    const float g = gamma[0];
    const size_t obase = (size_t)mi * SLICE;
#pragma unroll
    for (int ct = 0; ct < 8; ++ct) {
#pragma unroll
        for (int r = 0; r < 4; ++r) {
            int c = (ch * 8 + ct) * 16 + 4 * q + r;
            size_t off = obase + (size_t)c * NPIX + j16 + lj;
            out[off] = g * acc[ct][r] + x[off];
        }
    }
}

extern "C" void kernel_launch(void* const* d_in, const int* in_sizes, int n_in,
                              void* d_out, int out_size, void* d_ws, size_t ws_size,
                              hipStream_t stream)
{
    const float* x     = (const float*)d_in[0];
    const float* wq    = (const float*)d_in[1];
    const float* bq    = (const float*)d_in[2];
    const float* wk    = (const float*)d_in[3];
    const float* bk    = (const float*)d_in[4];
    const float* wv    = (const float*)d_in[5];
    const float* bv    = (const float*)d_in[6];
    const float* gamma = (const float*)d_in[7];
    float* out = (float*)d_out;

    char* wsb = (char*)d_ws;
    unsigned short* Wb = (unsigned short*)(wsb + WB_OFF);
    float*          a2 = (float*)(wsb + A2_OFF);
    unsigned short* Xt = (unsigned short*)(wsb + XT_OFF);
    unsigned short* Qt = (unsigned short*)(wsb + QT_OFF);
    unsigned short* Kt = (unsigned short*)(wsb + KT_OFF);
    unsigned short* V  = (unsigned short*)(wsb + V_OFF);

    k_prep_w<<<80, 256, 0, stream>>>(wq, wk, wv, Wb);
    k_prep_x<<<dim3(NPIX / 64, CCH / 64, MB), 256, 0, stream>>>(x, Xt);
    k_proj<<<dim3(NPIX / 64, 5, MB), 256, 0, stream>>>(Wb, Xt, bq, bk, bv, Qt, Kt, V);
    k_stats<<<dim3(NPIX / 64, MB), 256, 0, stream>>>(Qt, Kt, a2);
    k_attn_out<<<dim3(NPIX / 64, 2, MB), 256, 0, stream>>>(x, gamma, Qt, Kt, V, a2, out);
}

// Round 4
// 213.107 us; speedup vs baseline: 1.2911x; 1.2911x over previous
//
#include <hip/hip_runtime.h>

#define MB    32        // B*T slices
#define CCH   256       // channels C
#define QCH   32        // q/k channels
#define NPIX  1024      // W*H
#define SLICE (CCH * NPIX)   // 262144
#define L2E   1.44269504088896340736f
#define SHIFT 32.0f     // fixed softmax shift (log2-domain energies well within fp32 range)

typedef __bf16          bf16x8 __attribute__((ext_vector_type(8)));
typedef float           f32x4  __attribute__((ext_vector_type(4)));
typedef unsigned int    u32x4  __attribute__((ext_vector_type(4)));
typedef unsigned short  u16x4  __attribute__((ext_vector_type(4)));

__device__ __forceinline__ unsigned short f2bf(float f) {
    unsigned int u = __builtin_bit_cast(unsigned int, f);
    u += 0x7FFFu + ((u >> 16) & 1u);          // RTNE
    return (unsigned short)(u >> 16);
}
__device__ __forceinline__ bf16x8 ldfrag(const unsigned short* p) {
    u32x4 u = *(const u32x4*)p;
    return __builtin_bit_cast(bf16x8, u);
}

// workspace byte offsets (total ~38 MB, proven fits)
#define WB_OFF 0u                 // 320*256 bf16
#define A2_OFF 163840u            // 32*1024 f32
#define XT_OFF 294912u            // 32*1024*256 bf16
#define QT_OFF 17072128u          // 32*1024*32 bf16
#define KT_OFF 19169280u          // 32*1024*32 bf16
#define V_OFF  21266432u          // 32*256*1024 bf16 (MFMA A-fragment layout)

// ---------------------------------------------------------------------------
// K0w: convert stacked [wq;wk;wv] (320x256 f32) -> Wb bf16
// ---------------------------------------------------------------------------
__global__ __launch_bounds__(256) void k_prep_w(
    const float* __restrict__ wq, const float* __restrict__ wk,
    const float* __restrict__ wv, unsigned short* __restrict__ Wb)
{
    int i4 = (blockIdx.x * 256 + threadIdx.x) * 4;
    int o = i4 >> 8, c = i4 & 255;
    const float* src = (o < 32) ? wq + (size_t)o * CCH + c
                     : (o < 64) ? wk + (size_t)(o - 32) * CCH + c
                                : wv + (size_t)(o - 64) * CCH + c;
    float4 v = *(const float4*)src;
    u16x4 d = { f2bf(v.x), f2bf(v.y), f2bf(v.z), f2bf(v.w) };
    *(u16x4*)(Wb + i4) = d;
}

// ---------------------------------------------------------------------------
// K0x: transpose-convert x (f32 [c][n] per slice) -> Xt bf16 [n][c]
// ---------------------------------------------------------------------------
__global__ __launch_bounds__(256) void k_prep_x(
    const float* __restrict__ x, unsigned short* __restrict__ Xt)
{
    __shared__ unsigned short Ts[64][72];
    const int t = threadIdx.x;
    const int n0 = blockIdx.x * 64, c0 = blockIdx.y * 64, mi = blockIdx.z;
    const float* xp = x + (size_t)mi * SLICE;
    unsigned short* Xp = Xt + (size_t)mi * SLICE;
#pragma unroll
    for (int r = 0; r < 4; ++r) {
        int cl = (t >> 4) + r * 16;
        int nl = (t & 15) * 4;
        float4 v = *(const float4*)(xp + (size_t)(c0 + cl) * NPIX + n0 + nl);
        Ts[nl + 0][cl] = f2bf(v.x); Ts[nl + 1][cl] = f2bf(v.y);
        Ts[nl + 2][cl] = f2bf(v.z); Ts[nl + 3][cl] = f2bf(v.w);
    }
    __syncthreads();
#pragma unroll
    for (int r = 0; r < 4; ++r) {
        int nl = (t >> 4) + r * 16;
        int cl = (t & 15) * 4;
        u16x4 d = *(const u16x4*)&Ts[nl][cl];
        *(u16x4*)(Xp + (size_t)(n0 + nl) * CCH + c0 + cl) = d;
    }
}

// ---------------------------------------------------------------------------
// K1: MFMA projections, merged-o block. O(320x1024) = Wb @ Xt^T per slice.
// Block = n64 tile x ALL 320 o-rows; W + X staged in LDS per k32 chunk.
// Wave w owns o-tiles {w, w+4, w+8, w+12, w+16} x 4 n-frags = 20 MFMAs/chunk.
// Epilogue: o<32 -> Qt[n][o]*L2E+bq; o<64 -> Kt[n][o]+bk; else Vf frag layout.
// ---------------------------------------------------------------------------
__global__ __launch_bounds__(256) void k_proj(
    const unsigned short* __restrict__ Wb, const unsigned short* __restrict__ Xt,
    const float* __restrict__ bq, const float* __restrict__ bk,
    const float* __restrict__ bv,
    unsigned short* __restrict__ Qt, unsigned short* __restrict__ Kt,
    unsigned short* __restrict__ V)
{
    __shared__ unsigned short Wsh[320 * 36];   // [o][k32], pitch 36 (18 banks)
    __shared__ unsigned short Xs[64 * 36];     // [n][k32], pitch 36

    const int t = threadIdx.x, lane = t & 63, w = t >> 6;
    const int lj = lane & 15, q = lane >> 4;
    const int n0 = blockIdx.x * 64;
    const int mi = blockIdx.y;
    const unsigned short* Xp = Xt + (size_t)mi * SLICE;

    f32x4 acc[5][4];
#pragma unroll
    for (int i = 0; i < 5; ++i)
#pragma unroll
        for (int b = 0; b < 4; ++b) acc[i][b] = (f32x4){0.f, 0.f, 0.f, 0.f};

    for (int kc = 0; kc < CCH; kc += 32) {
        __syncthreads();
        // stage X: 64 rows x 32k  (4 b128 per row)
        {
            int row = t >> 2, part = t & 3;
            u32x4 d = *(const u32x4*)(Xp + (size_t)(n0 + row) * CCH + kc + part * 8);
            *(u32x4*)&Xs[row * 36 + part * 8] = d;
        }
        // stage W: 320 rows x 32k = 1280 b128
#pragma unroll
        for (int i = 0; i < 5; ++i) {
            int f = t + i * 256;
            int row = f >> 2, part = f & 3;
            u32x4 d = *(const u32x4*)(Wb + (size_t)row * CCH + kc + part * 8);
            *(u32x4*)&Wsh[row * 36 + part * 8] = d;
        }
        __syncthreads();

        bf16x8 xb[4];
#pragma unroll
        for (int b = 0; b < 4; ++b)
            xb[b] = ldfrag(&Xs[(b * 16 + lj) * 36 + q * 8]);
#pragma unroll
        for (int i = 0; i < 5; ++i) {
            int ot = w + 4 * i;
            bf16x8 a = ldfrag(&Wsh[(ot * 16 + lj) * 36 + q * 8]);
#pragma unroll
            for (int b = 0; b < 4; ++b)
                acc[i][b] = __builtin_amdgcn_mfma_f32_16x16x32_bf16(a, xb[b], acc[i][b], 0, 0, 0);
        }
    }

#pragma unroll
    for (int i = 0; i < 5; ++i) {
        const int o16 = (w + 4 * i) * 16;
        const int ob = o16 + 4 * q;
        if (o16 < 32) {                    // Q -> Qt[n][o], pre-scaled by log2(e)
            unsigned short* Qp = Qt + (size_t)mi * NPIX * QCH;
            float b0 = bq[ob], b1 = bq[ob + 1], b2 = bq[ob + 2], b3 = bq[ob + 3];
#pragma unroll
            for (int b = 0; b < 4; ++b) {
                int n = n0 + b * 16 + lj;
                u16x4 d = { f2bf((acc[i][b][0] + b0) * L2E), f2bf((acc[i][b][1] + b1) * L2E),
                            f2bf((acc[i][b][2] + b2) * L2E), f2bf((acc[i][b][3] + b3) * L2E) };
                *(u16x4*)(Qp + (size_t)n * QCH + ob) = d;
            }
        } else if (o16 < 64) {             // K -> Kt[n][o]
            unsigned short* Kp = Kt + (size_t)mi * NPIX * QCH;
            int o2 = ob - 32;
            float b0 = bk[o2], b1 = bk[o2 + 1], b2 = bk[o2 + 2], b3 = bk[o2 + 3];
#pragma unroll
            for (int b = 0; b < 4; ++b) {
                int n = n0 + b * 16 + lj;
                u16x4 d = { f2bf(acc[i][b][0] + b0), f2bf(acc[i][b][1] + b1),
                            f2bf(acc[i][b][2] + b2), f2bf(acc[i][b][3] + b3) };
                *(u16x4*)(Kp + (size_t)n * QCH + o2) = d;
            }
        } else {                           // V -> fragment layout (verified r3)
            unsigned short* Vw = V + (size_t)mi * SLICE;
            const int c16 = (o16 - 64) >> 4;
            const int n05 = n0 >> 5;
            const int cb = (o16 - 64) + 4 * q;
            float bb[4] = { bv[cb], bv[cb + 1], bv[cb + 2], bv[cb + 3] };
            const int ni = lj & 7;
#pragma unroll
            for (int b = 0; b < 4; ++b) {
                int n5 = n05 + (b >> 1);
                int fl = ((2 * b + (lj >> 3)) & 3) * 16 + 4 * q;
                size_t base = ((size_t)(c16 * 32 + n5) * 64 + fl) * 8 + ni;
#pragma unroll
                for (int r = 0; r < 4; ++r)
                    Vw[base + (size_t)r * 8] = f2bf(acc[i][b][r] + bb[r]);
            }
        }
    }
}

// ---------------------------------------------------------------------------
// K2: softmax row sums, fixed shift. Same mfma tiles as K3 -> consistent E.
// a2[n] = SHIFT + log2(S).
// ---------------------------------------------------------------------------
__global__ __launch_bounds__(256) void k_stats(
    const unsigned short* __restrict__ Qt, const unsigned short* __restrict__ Kt,
    float* __restrict__ a2f)
{
    const int t = threadIdx.x, lane = t & 63, w = t >> 6;
    const int lj = lane & 15, q = lane >> 4;
    const int n16 = blockIdx.x * 64 + w * 16;
    const int mi = blockIdx.y;
    const unsigned short* Qp = Qt + (size_t)mi * NPIX * QCH;
    const unsigned short* Kp = Kt + (size_t)mi * NPIX * QCH;

    bf16x8 qa = ldfrag(Qp + (size_t)(n16 + lj) * QCH + q * 8);

    float s[4] = { 0.f, 0.f, 0.f, 0.f };
#pragma unroll 8
    for (int jc = 0; jc < NPIX; jc += 16) {
        bf16x8 kb = ldfrag(Kp + (size_t)(jc + lj) * QCH + q * 8);
        f32x4 z = (f32x4){0.f, 0.f, 0.f, 0.f};
        f32x4 e = __builtin_amdgcn_mfma_f32_16x16x32_bf16(qa, kb, z, 0, 0, 0);
#pragma unroll
        for (int r = 0; r < 4; ++r) s[r] += exp2f(e[r] - SHIFT);
    }
#pragma unroll
    for (int msk = 1; msk <= 8; msk <<= 1)
#pragma unroll
        for (int r = 0; r < 4; ++r) s[r] += __shfl_xor(s[r], msk, 64);

    if (lj == 0) {
        float* apo = a2f + (size_t)mi * NPIX;
#pragma unroll
        for (int r = 0; r < 4; ++r)
            apo[n16 + 4 * q + r] = SHIFT + log2f(s[r]);
    }
}

// ---------------------------------------------------------------------------
// K3: fused second pass, 2-D tiled GEMM. Block = c128 x j128 per slice.
// Per n32 chunk: stage V frags (8KB, contiguous) -> wave computes its
// n32 x j32 E strip (Kt frags register-resident) -> P to padded LDS ->
// O-phase: wave = c64 x j64, 8 LDS frag reads -> 16 MFMAs (0.5 reads/MFMA).
// ---------------------------------------------------------------------------
__global__ __launch_bounds__(256) void k_attn_out(
    const float* __restrict__ x, const float* __restrict__ gamma,
    const unsigned short* __restrict__ Qt, const unsigned short* __restrict__ Kt,
    const unsigned short* __restrict__ Vf, const float* __restrict__ a2f,
    float* __restrict__ out)
{
    __shared__ unsigned short Vs[8 * 512];    // 8 c-frags x 1KB, frag-contiguous
    __shared__ unsigned short Ps[128 * 36];   // P [j][n32], pitch 36 (18 banks)

    const int t = threadIdx.x, lane = t & 63, w = t >> 6;
    const int lj = lane & 15, q = lane >> 4;
    const int j0 = blockIdx.x * 128;
    const int cb = blockIdx.y;                // c-half 0/1
    const int mi = blockIdx.z;

    const unsigned short* Qp = Qt + (size_t)mi * NPIX * QCH;
    const unsigned short* Kp = Kt + (size_t)mi * NPIX * QCH;
    const unsigned short* Vp = Vf + (size_t)mi * SLICE;
    const float* ap = a2f + (size_t)mi * NPIX;

    // Kt frags for this wave's j32 E-strip: register-resident for whole loop
    bf16x8 kb[2];
#pragma unroll
    for (int sj = 0; sj < 2; ++sj)
        kb[sj] = ldfrag(Kp + (size_t)(j0 + w * 32 + sj * 16 + lj) * QCH + q * 8);

    const int wc = w >> 1, wj = w & 1;        // O-phase: wave = c64 x j64
    const int cb8 = cb * 8;

    f32x4 acc[4][4];
#pragma unroll
    for (int ci = 0; ci < 4; ++ci)
#pragma unroll
        for (int ji = 0; ji < 4; ++ji) acc[ci][ji] = (f32x4){0.f, 0.f, 0.f, 0.f};

    for (int nc = 0; nc < NPIX; nc += 32) {
        __syncthreads();                       // prev O-phase reads done
        // stage V frags (cb8..cb8+7, n5) -> Vs, contiguous 32B per thread
        {
            const int ctl = t >> 5, ln0 = (t & 31) * 2;
            const unsigned short* src =
                Vp + ((size_t)(cb8 + ctl) * 32 + (nc >> 5)) * 512 + ln0 * 8;
            u32x4 d0 = *(const u32x4*)src;
            u32x4 d1 = *(const u32x4*)(src + 8);
            *(u32x4*)&Vs[ctl * 512 + ln0 * 8] = d0;
            *(u32x4*)&Vs[ctl * 512 + ln0 * 8 + 8] = d1;
        }
        // E phase: this wave's n32 x j32 strip -> P into Ps[j][n]
#pragma unroll
        for (int sn = 0; sn < 2; ++sn) {
            int nr = nc + sn * 16;
            bf16x8 qa = ldfrag(Qp + (size_t)(nr + lj) * QCH + q * 8);
            f32x4 a4 = *(const f32x4*)(ap + nr + 4 * q);
#pragma unroll
            for (int sj = 0; sj < 2; ++sj) {
                f32x4 z = (f32x4){0.f, 0.f, 0.f, 0.f};
                f32x4 e = __builtin_amdgcn_mfma_f32_16x16x32_bf16(qa, kb[sj], z, 0, 0, 0);
                u16x4 pv = { f2bf(exp2f(e[0] - a4[0])), f2bf(exp2f(e[1] - a4[1])),
                             f2bf(exp2f(e[2] - a4[2])), f2bf(exp2f(e[3] - a4[3])) };
                *(u16x4*)&Ps[(w * 32 + sj * 16 + lj) * 36 + sn * 16 + 4 * q] = pv;
            }
        }
        __syncthreads();                       // Vs + Ps visible

        // O phase: 4 V-frags + 4 P-frags -> 16 MFMAs
        bf16x8 pf[4];
#pragma unroll
        for (int ji = 0; ji < 4; ++ji)
            pf[ji] = ldfrag(&Ps[(wj * 64 + ji * 16 + lj) * 36 + q * 8]);
#pragma unroll
        for (int ci = 0; ci < 4; ++ci) {
            bf16x8 vfr = ldfrag(&Vs[(wc * 4 + ci) * 512 + lane * 8]);
#pragma unroll
            for (int ji = 0; ji < 4; ++ji)
                acc[ci][ji] = __builtin_amdgcn_mfma_f32_16x16x32_bf16(vfr, pf[ji], acc[ci][ji], 0, 0, 0);
        }
    }

    const float g = gamma[0];
    const size_t obase = (size_t)mi * SLICE;
#pragma unroll
    for (int ci = 0; ci < 4; ++ci) {
#pragma unroll
        for (int ji = 0; ji < 4; ++ji) {
#pragma unroll
            for (int r = 0; r < 4; ++r) {
                int c = cb * 128 + (wc * 4 + ci) * 16 + 4 * q + r;
                int j = j0 + wj * 64 + ji * 16 + lj;
                size_t off = obase + (size_t)c * NPIX + j;
                out[off] = g * acc[ci][ji][r] + x[off];
            }
        }
    }
}

extern "C" void kernel_launch(void* const* d_in, const int* in_sizes, int n_in,
                              void* d_out, int out_size, void* d_ws, size_t ws_size,
                              hipStream_t stream)
{
    const float* x     = (const float*)d_in[0];
    const float* wq    = (const float*)d_in[1];
    const float* bq    = (const float*)d_in[2];
    const float* wk    = (const float*)d_in[3];
    const float* bk    = (const float*)d_in[4];
    const float* wv    = (const float*)d_in[5];
    const float* bv    = (const float*)d_in[6];
    const float* gamma = (const float*)d_in[7];
    float* out = (float*)d_out;

    char* wsb = (char*)d_ws;
    unsigned short* Wb = (unsigned short*)(wsb + WB_OFF);
    float*          a2 = (float*)(wsb + A2_OFF);
    unsigned short* Xt = (unsigned short*)(wsb + XT_OFF);
    unsigned short* Qt = (unsigned short*)(wsb + QT_OFF);
    unsigned short* Kt = (unsigned short*)(wsb + KT_OFF);
    unsigned short* V  = (unsigned short*)(wsb + V_OFF);

    k_prep_w<<<80, 256, 0, stream>>>(wq, wk, wv, Wb);
    k_prep_x<<<dim3(NPIX / 64, CCH / 64, MB), 256, 0, stream>>>(x, Xt);
    k_proj<<<dim3(NPIX / 64, MB), 256, 0, stream>>>(Wb, Xt, bq, bk, bv, Qt, Kt, V);
    k_stats<<<dim3(NPIX / 64, MB), 256, 0, stream>>>(Qt, Kt, a2);
    k_attn_out<<<dim3(NPIX / 128, 2, MB), 256, 0, stream>>>(x, gamma, Qt, Kt, V, a2, out);
}

// Round 5
// 182.185 us; speedup vs baseline: 1.5102x; 1.1697x over previous
//
#include <hip/hip_runtime.h>

#define MB    32        // B*T slices
#define CCH   256       // channels C
#define QCH   32        // q/k channels
#define NPIX  1024      // W*H
#define SLICE (CCH * NPIX)   // 262144
#define L2E   1.44269504088896340736f
#define SHIFT 32.0f     // fixed softmax shift (log2-domain energies well within fp32 range)

typedef __bf16          bf16x8 __attribute__((ext_vector_type(8)));
typedef __bf16          bf16x4 __attribute__((ext_vector_type(4)));
typedef float           f32x4  __attribute__((ext_vector_type(4)));
typedef unsigned int    u32x4  __attribute__((ext_vector_type(4)));
typedef unsigned short  u16x4  __attribute__((ext_vector_type(4)));

__device__ __forceinline__ unsigned short f2bf(float f) {
    unsigned int u = __builtin_bit_cast(unsigned int, f);
    u += 0x7FFFu + ((u >> 16) & 1u);          // RTNE
    return (unsigned short)(u >> 16);
}
// HW packed cvt path (v_cvt_pk_bf16_f32 on gfx950), RTNE — same numerics as f2bf
__device__ __forceinline__ u16x4 cvt4(float a, float b, float c, float d) {
    bf16x4 v = { (__bf16)a, (__bf16)b, (__bf16)c, (__bf16)d };
    return __builtin_bit_cast(u16x4, v);
}
__device__ __forceinline__ bf16x8 ldfrag(const unsigned short* p) {
    u32x4 u = *(const u32x4*)p;
    return __builtin_bit_cast(bf16x8, u);
}

// workspace byte offsets (total ~38 MB)
#define WB_OFF 0u                 // 320*256 bf16
#define A2_OFF 163840u            // 32*1024 f32
#define XT_OFF 294912u            // 32*1024*256 bf16
#define QT_OFF 17072128u          // 32*1024*32 bf16
#define KT_OFF 19169280u          // 32*1024*32 bf16
#define V_OFF  21266432u          // 32*256*1024 bf16 (MFMA A-fragment layout)

// ---------------------------------------------------------------------------
// K0w: convert stacked [wq;wk;wv] (320x256 f32) -> Wb bf16
// ---------------------------------------------------------------------------
__global__ __launch_bounds__(256) void k_prep_w(
    const float* __restrict__ wq, const float* __restrict__ wk,
    const float* __restrict__ wv, unsigned short* __restrict__ Wb)
{
    int i4 = (blockIdx.x * 256 + threadIdx.x) * 4;
    int o = i4 >> 8, c = i4 & 255;
    const float* src = (o < 32) ? wq + (size_t)o * CCH + c
                     : (o < 64) ? wk + (size_t)(o - 32) * CCH + c
                                : wv + (size_t)(o - 64) * CCH + c;
    float4 v = *(const float4*)src;
    *(u16x4*)(Wb + i4) = cvt4(v.x, v.y, v.z, v.w);
}

// ---------------------------------------------------------------------------
// K0x: transpose-convert x (f32 [c][n] per slice) -> Xt bf16 [n][c]
// ---------------------------------------------------------------------------
__global__ __launch_bounds__(256) void k_prep_x(
    const float* __restrict__ x, unsigned short* __restrict__ Xt)
{
    __shared__ unsigned short Ts[64][72];
    const int t = threadIdx.x;
    const int n0 = blockIdx.x * 64, c0 = blockIdx.y * 64, mi = blockIdx.z;
    const float* xp = x + (size_t)mi * SLICE;
    unsigned short* Xp = Xt + (size_t)mi * SLICE;
#pragma unroll
    for (int r = 0; r < 4; ++r) {
        int cl = (t >> 4) + r * 16;
        int nl = (t & 15) * 4;
        float4 v = *(const float4*)(xp + (size_t)(c0 + cl) * NPIX + n0 + nl);
        Ts[nl + 0][cl] = f2bf(v.x); Ts[nl + 1][cl] = f2bf(v.y);
        Ts[nl + 2][cl] = f2bf(v.z); Ts[nl + 3][cl] = f2bf(v.w);
    }
    __syncthreads();
#pragma unroll
    for (int r = 0; r < 4; ++r) {
        int nl = (t >> 4) + r * 16;
        int cl = (t & 15) * 4;
        u16x4 d = *(const u16x4*)&Ts[nl][cl];
        *(u16x4*)(Xp + (size_t)(n0 + nl) * CCH + c0 + cl) = d;
    }
}

// ---------------------------------------------------------------------------
// K1: MFMA projections. O(320x1024) = Wb @ Xt^T per slice.
// X tile (n64 x K256) staged ONCE in LDS; W read directly from global
// (160KB, L1/L2-hot). Zero barriers in the K-loop. Wave w owns o-tiles
// {w,w+4,w+8,w+12,w+16} x 4 n-frags = 20 MFMA per k32 chunk.
// ---------------------------------------------------------------------------
__global__ __launch_bounds__(256) void k_proj(
    const unsigned short* __restrict__ Wb, const unsigned short* __restrict__ Xt,
    const float* __restrict__ bq, const float* __restrict__ bk,
    const float* __restrict__ bv,
    unsigned short* __restrict__ Qt, unsigned short* __restrict__ Kt,
    unsigned short* __restrict__ V)
{
    __shared__ unsigned short Xs[64 * 268];   // [n][k256], pitch 268 (stride 6 banks)

    const int t = threadIdx.x, lane = t & 63, w = t >> 6;
    const int lj = lane & 15, q = lane >> 4;
    const int n0 = blockIdx.x * 64;
    const int mi = blockIdx.y;
    const unsigned short* Xp = Xt + (size_t)mi * SLICE;

    // stage X once: 64 rows x 256 u16 = 32KB
#pragma unroll
    for (int r = 0; r < 8; ++r) {
        int idx = t + r * 256;
        int row = idx >> 5, seg = idx & 31;
        u32x4 d = *(const u32x4*)(Xp + (size_t)(n0 + row) * CCH + seg * 8);
        *(u32x4*)&Xs[row * 268 + seg * 8] = d;
    }
    __syncthreads();

    f32x4 acc[5][4];
#pragma unroll
    for (int i = 0; i < 5; ++i)
#pragma unroll
        for (int b = 0; b < 4; ++b) acc[i][b] = (f32x4){0.f, 0.f, 0.f, 0.f};

    const unsigned short* wbase = Wb + (size_t)(w * 16 + lj) * CCH + q * 8;
    const unsigned short* xbase = &Xs[lj * 268 + q * 8];

#pragma unroll 2
    for (int kc = 0; kc < CCH; kc += 32) {
        bf16x8 a[5];
#pragma unroll
        for (int i = 0; i < 5; ++i)
            a[i] = ldfrag(wbase + (size_t)i * 64 * CCH + kc);
        bf16x8 xb[4];
#pragma unroll
        for (int b = 0; b < 4; ++b)
            xb[b] = ldfrag(xbase + b * 16 * 268 + kc);
#pragma unroll
        for (int i = 0; i < 5; ++i)
#pragma unroll
            for (int b = 0; b < 4; ++b)
                acc[i][b] = __builtin_amdgcn_mfma_f32_16x16x32_bf16(a[i], xb[b], acc[i][b], 0, 0, 0);
    }

#pragma unroll
    for (int i = 0; i < 5; ++i) {
        const int o16 = (w + 4 * i) * 16;
        const int ob = o16 + 4 * q;
        if (o16 < 32) {                    // Q -> Qt[n][o], pre-scaled by log2(e)
            unsigned short* Qp = Qt + (size_t)mi * NPIX * QCH;
            float b0 = bq[ob], b1 = bq[ob + 1], b2 = bq[ob + 2], b3 = bq[ob + 3];
#pragma unroll
            for (int b = 0; b < 4; ++b) {
                int n = n0 + b * 16 + lj;
                *(u16x4*)(Qp + (size_t)n * QCH + ob) =
                    cvt4((acc[i][b][0] + b0) * L2E, (acc[i][b][1] + b1) * L2E,
                         (acc[i][b][2] + b2) * L2E, (acc[i][b][3] + b3) * L2E);
            }
        } else if (o16 < 64) {             // K -> Kt[n][o]
            unsigned short* Kp = Kt + (size_t)mi * NPIX * QCH;
            int o2 = ob - 32;
            float b0 = bk[o2], b1 = bk[o2 + 1], b2 = bk[o2 + 2], b3 = bk[o2 + 3];
#pragma unroll
            for (int b = 0; b < 4; ++b) {
                int n = n0 + b * 16 + lj;
                *(u16x4*)(Kp + (size_t)n * QCH + o2) =
                    cvt4(acc[i][b][0] + b0, acc[i][b][1] + b1,
                         acc[i][b][2] + b2, acc[i][b][3] + b3);
            }
        } else {                           // V -> fragment layout (verified r3/r4)
            unsigned short* Vw = V + (size_t)mi * SLICE;
            const int c16 = (o16 - 64) >> 4;
            const int n05 = n0 >> 5;
            const int cb = (o16 - 64) + 4 * q;
            float bb[4] = { bv[cb], bv[cb + 1], bv[cb + 2], bv[cb + 3] };
            const int ni = lj & 7;
#pragma unroll
            for (int b = 0; b < 4; ++b) {
                int n5 = n05 + (b >> 1);
                int fl = ((2 * b + (lj >> 3)) & 3) * 16 + 4 * q;
                size_t base = ((size_t)(c16 * 32 + n5) * 64 + fl) * 8 + ni;
#pragma unroll
                for (int r = 0; r < 4; ++r)
                    Vw[base + (size_t)r * 8] = f2bf(acc[i][b][r] + bb[r]);
            }
        }
    }
}

// ---------------------------------------------------------------------------
// K2: softmax row sums, fixed shift. Same mfma tiles as K3 -> consistent E.
// a2[n] = SHIFT + log2(S).
// ---------------------------------------------------------------------------
__global__ __launch_bounds__(256) void k_stats(
    const unsigned short* __restrict__ Qt, const unsigned short* __restrict__ Kt,
    float* __restrict__ a2f)
{
    const int t = threadIdx.x, lane = t & 63, w = t >> 6;
    const int lj = lane & 15, q = lane >> 4;
    const int n16 = blockIdx.x * 64 + w * 16;
    const int mi = blockIdx.y;
    const unsigned short* Qp = Qt + (size_t)mi * NPIX * QCH;
    const unsigned short* Kp = Kt + (size_t)mi * NPIX * QCH;

    bf16x8 qa = ldfrag(Qp + (size_t)(n16 + lj) * QCH + q * 8);

    float s[4] = { 0.f, 0.f, 0.f, 0.f };
#pragma unroll 8
    for (int jc = 0; jc < NPIX; jc += 16) {
        bf16x8 kb = ldfrag(Kp + (size_t)(jc + lj) * QCH + q * 8);
        f32x4 z = (f32x4){0.f, 0.f, 0.f, 0.f};
        f32x4 e = __builtin_amdgcn_mfma_f32_16x16x32_bf16(qa, kb, z, 0, 0, 0);
#pragma unroll
        for (int r = 0; r < 4; ++r) s[r] += exp2f(e[r] - SHIFT);
    }
#pragma unroll
    for (int msk = 1; msk <= 8; msk <<= 1)
#pragma unroll
        for (int r = 0; r < 4; ++r) s[r] += __shfl_xor(s[r], msk, 64);

    if (lj == 0) {
        float* apo = a2f + (size_t)mi * NPIX;
#pragma unroll
        for (int r = 0; r < 4; ++r)
            apo[n16 + 4 * q + r] = SHIFT + log2f(s[r]);
    }
}

// ---------------------------------------------------------------------------
// K3: fused second pass. Block = j128 x c128; wave = its own j32 x c128
// (Ps wave-private -> no barrier for P). Vs double-buffered -> ONE barrier
// per n32 chunk. Next chunk's V/Q/a2 prefetched across the O-phase.
// XCD swizzle: all 16 blocks of a slice share (blockIdx%8) -> same XCD L2.
// ---------------------------------------------------------------------------
__global__ __launch_bounds__(256) void k_attn_out(
    const float* __restrict__ x, const float* __restrict__ gamma,
    const unsigned short* __restrict__ Qt, const unsigned short* __restrict__ Kt,
    const unsigned short* __restrict__ Vf, const float* __restrict__ a2f,
    float* __restrict__ out)
{
    __shared__ unsigned short Vs[2][8 * 512];   // dbuf: 8 c-frags x 1KB
    __shared__ unsigned short Ps[4][32][36];    // per-wave P [j32][n32], pitch 36

    const int b = blockIdx.x;
    const int mi  = (b & 7) | ((b >> 7) << 3);  // slice: same (b%8) -> same XCD
    const int sub = (b >> 3) & 15;
    const int j0  = (sub & 7) * 128;
    const int cb  = sub >> 3;                   // c-half 0/1

    const int t = threadIdx.x, lane = t & 63, w = t >> 6;
    const int lj = lane & 15, q = lane >> 4;
    const int jw = j0 + w * 32;                 // this wave's j32

    const unsigned short* Qp = Qt + (size_t)mi * NPIX * QCH;
    const unsigned short* Kp = Kt + (size_t)mi * NPIX * QCH;
    const unsigned short* Vp = Vf + (size_t)mi * SLICE;
    const float* ap = a2f + (size_t)mi * NPIX;

    // Kt frags for this wave's j32: register-resident for the whole loop
    bf16x8 kb[2];
#pragma unroll
    for (int sj = 0; sj < 2; ++sj)
        kb[sj] = ldfrag(Kp + (size_t)(jw + sj * 16 + lj) * QCH + q * 8);

    // V stage addressing (thread-level): frag ctl, 32B at ln0
    const int ctl = t >> 5, ln0 = (t & 31) * 2;
    const unsigned short* vsrc0 = Vp + ((size_t)(cb * 8 + ctl) * 32) * 512 + ln0 * 8;

    f32x4 acc[8][2];
#pragma unroll
    for (int ci = 0; ci < 8; ++ci)
#pragma unroll
        for (int ji = 0; ji < 2; ++ji) acc[ci][ji] = (f32x4){0.f, 0.f, 0.f, 0.f};

    // prestage chunk 0
    {
        u32x4 d0 = *(const u32x4*)vsrc0;
        u32x4 d1 = *(const u32x4*)(vsrc0 + 8);
        *(u32x4*)&Vs[0][ctl * 512 + ln0 * 8] = d0;
        *(u32x4*)&Vs[0][ctl * 512 + ln0 * 8 + 8] = d1;
    }
    // preload chunk 0 Q frags + a2
    bf16x8 qa_n[2];
    f32x4  a4_n[2];
#pragma unroll
    for (int sn = 0; sn < 2; ++sn) {
        qa_n[sn] = ldfrag(Qp + (size_t)(sn * 16 + lj) * QCH + q * 8);
        a4_n[sn] = *(const f32x4*)(ap + sn * 16 + 4 * q);
    }
    __syncthreads();

    int p = 0;
    for (int nc = 0; nc < NPIX; nc += 32, p ^= 1) {
        const int nn = (nc + 32) & (NPIX - 1);   // next chunk (wrapped; harmless tail)
        // issue next V loads early
        const unsigned short* vsrc = vsrc0 + (size_t)(nn >> 5) * 512;
        u32x4 nv0 = *(const u32x4*)vsrc;
        u32x4 nv1 = *(const u32x4*)(vsrc + 8);

        // E phase: wave's n32 x j32 strip -> P into wave-private Ps
        bf16x8 qa0 = qa_n[0], qa1 = qa_n[1];
        f32x4 a40 = a4_n[0], a41 = a4_n[1];
#pragma unroll
        for (int sj = 0; sj < 2; ++sj) {
            f32x4 z = (f32x4){0.f, 0.f, 0.f, 0.f};
            f32x4 e0 = __builtin_amdgcn_mfma_f32_16x16x32_bf16(qa0, kb[sj], z, 0, 0, 0);
            f32x4 e1 = __builtin_amdgcn_mfma_f32_16x16x32_bf16(qa1, kb[sj], z, 0, 0, 0);
            *(u16x4*)&Ps[w][sj * 16 + lj][4 * q] =
                cvt4(exp2f(e0[0] - a40[0]), exp2f(e0[1] - a40[1]),
                     exp2f(e0[2] - a40[2]), exp2f(e0[3] - a40[3]));
            *(u16x4*)&Ps[w][sj * 16 + lj][16 + 4 * q] =
                cvt4(exp2f(e1[0] - a41[0]), exp2f(e1[1] - a41[1]),
                     exp2f(e1[2] - a41[2]), exp2f(e1[3] - a41[3]));
        }
        // preload next chunk's Q frags + a2 (latency hidden by O phase)
#pragma unroll
        for (int sn = 0; sn < 2; ++sn) {
            qa_n[sn] = ldfrag(Qp + (size_t)(nn + sn * 16 + lj) * QCH + q * 8);
            a4_n[sn] = *(const f32x4*)(ap + nn + sn * 16 + 4 * q);
        }

        // O phase: 16 MFMA from Vs[p] + wave-private Ps
        bf16x8 pf[2];
#pragma unroll
        for (int ji = 0; ji < 2; ++ji)
            pf[ji] = ldfrag(&Ps[w][ji * 16 + lj][q * 8]);
#pragma unroll
        for (int ci = 0; ci < 8; ++ci) {
            bf16x8 vfr = ldfrag(&Vs[p][ci * 512 + lane * 8]);
#pragma unroll
            for (int ji = 0; ji < 2; ++ji)
                acc[ci][ji] = __builtin_amdgcn_mfma_f32_16x16x32_bf16(vfr, pf[ji], acc[ci][ji], 0, 0, 0);
        }

        // write next chunk's V into the other buffer; single barrier
        *(u32x4*)&Vs[p ^ 1][ctl * 512 + ln0 * 8] = nv0;
        *(u32x4*)&Vs[p ^ 1][ctl * 512 + ln0 * 8 + 8] = nv1;
        __syncthreads();
    }

    const float g = gamma[0];
    const size_t obase = (size_t)mi * SLICE;
#pragma unroll
    for (int ci = 0; ci < 8; ++ci) {
#pragma unroll
        for (int ji = 0; ji < 2; ++ji) {
#pragma unroll
            for (int r = 0; r < 4; ++r) {
                int c = cb * 128 + ci * 16 + 4 * q + r;
                int j = jw + ji * 16 + lj;
                size_t off = obase + (size_t)c * NPIX + j;
                out[off] = g * acc[ci][ji][r] + x[off];
            }
        }
    }
}

extern "C" void kernel_launch(void* const* d_in, const int* in_sizes, int n_in,
                              void* d_out, int out_size, void* d_ws, size_t ws_size,
                              hipStream_t stream)
{
    const float* x     = (const float*)d_in[0];
    const float* wq    = (const float*)d_in[1];
    const float* bq    = (const float*)d_in[2];
    const float* wk    = (const float*)d_in[3];
    const float* bk    = (const float*)d_in[4];
    const float* wv    = (const float*)d_in[5];
    const float* bv    = (const float*)d_in[6];
    const float* gamma = (const float*)d_in[7];
    float* out = (float*)d_out;

    char* wsb = (char*)d_ws;
    unsigned short* Wb = (unsigned short*)(wsb + WB_OFF);
    float*          a2 = (float*)(wsb + A2_OFF);
    unsigned short* Xt = (unsigned short*)(wsb + XT_OFF);
    unsigned short* Qt = (unsigned short*)(wsb + QT_OFF);
    unsigned short* Kt = (unsigned short*)(wsb + KT_OFF);
    unsigned short* V  = (unsigned short*)(wsb + V_OFF);

    k_prep_w<<<80, 256, 0, stream>>>(wq, wk, wv, Wb);
    k_prep_x<<<dim3(NPIX / 64, CCH / 64, MB), 256, 0, stream>>>(x, Xt);
    k_proj<<<dim3(NPIX / 64, MB), 256, 0, stream>>>(Wb, Xt, bq, bk, bv, Qt, Kt, V);
    k_stats<<<dim3(NPIX / 64, MB), 256, 0, stream>>>(Qt, Kt, a2);
    k_attn_out<<<512, 256, 0, stream>>>(x, gamma, Qt, Kt, V, a2, out);
}

// Round 6
// 168.478 us; speedup vs baseline: 1.6331x; 1.0814x over previous
//
#include <hip/hip_runtime.h>

#define MB    32        // B*T slices
#define CCH   256       // channels C
#define QCH   32        // q/k channels
#define NPIX  1024      // W*H
#define SLICE (CCH * NPIX)   // 262144
#define L2E   1.44269504088896340736f
#define SHIFT 32.0f     // fixed softmax shift (log2-domain energies well within fp32 range)

typedef __bf16          bf16x8 __attribute__((ext_vector_type(8)));
typedef __bf16          bf16x4 __attribute__((ext_vector_type(4)));
typedef float           f32x4  __attribute__((ext_vector_type(4)));
typedef unsigned int    u32x4  __attribute__((ext_vector_type(4)));
typedef unsigned short  u16x4  __attribute__((ext_vector_type(4)));

__device__ __forceinline__ unsigned short f2bf(float f) {
    unsigned int u = __builtin_bit_cast(unsigned int, f);
    u += 0x7FFFu + ((u >> 16) & 1u);          // RTNE
    return (unsigned short)(u >> 16);
}
__device__ __forceinline__ u16x4 cvt4(float a, float b, float c, float d) {
    bf16x4 v = { (__bf16)a, (__bf16)b, (__bf16)c, (__bf16)d };   // v_cvt_pk_bf16_f32
    return __builtin_bit_cast(u16x4, v);
}
__device__ __forceinline__ float bf2f(unsigned short u) {
    unsigned int v = (unsigned int)u << 16;
    return __builtin_bit_cast(float, v);
}
__device__ __forceinline__ bf16x8 ldfrag(const unsigned short* p) {
    u32x4 u = *(const u32x4*)p;
    return __builtin_bit_cast(bf16x8, u);
}

// workspace byte offsets
#define WB_OFF  0u              // 320*256 bf16 = 163840
#define QT_OFF  262144u         // 2 MB
#define KT_OFF  2359296u        // 2 MB
#define V_OFF   4456448u        // 16 MB (MFMA A-frag layout)
#define A2F_OFF 21233664u       // 128 KB (fallback path only)
#define PU_OFF  21364736u       // 64 MB (primary path only: Pu B-frags)
#define WS_NEED 88473600u

// ---------------------------------------------------------------------------
// K0w: convert stacked [wq;wk;wv] (320x256 f32) -> Wb bf16
// ---------------------------------------------------------------------------
__global__ __launch_bounds__(256) void k_prep_w(
    const float* __restrict__ wq, const float* __restrict__ wk,
    const float* __restrict__ wv, unsigned short* __restrict__ Wb)
{
    int i4 = (blockIdx.x * 256 + threadIdx.x) * 4;
    int o = i4 >> 8, c = i4 & 255;
    const float* src = (o < 32) ? wq + (size_t)o * CCH + c
                     : (o < 64) ? wk + (size_t)(o - 32) * CCH + c
                                : wv + (size_t)(o - 64) * CCH + c;
    float4 v = *(const float4*)src;
    *(u16x4*)(Wb + i4) = cvt4(v.x, v.y, v.z, v.w);
}

// ---------------------------------------------------------------------------
// K1: MFMA projections with FUSED x transpose+cvt (no Xt round-trip).
// Stage x[c][n0..63] f32 -> Xs[n][c] bf16 once; zero-barrier K-loop with
// W A-frags direct from global (L2-hot). Epilogues as r5 (verified).
// ---------------------------------------------------------------------------
__global__ __launch_bounds__(256) void k_proj(
    const float* __restrict__ x, const unsigned short* __restrict__ Wb,
    const float* __restrict__ bq, const float* __restrict__ bk,
    const float* __restrict__ bv,
    unsigned short* __restrict__ Qt, unsigned short* __restrict__ Kt,
    unsigned short* __restrict__ V)
{
    __shared__ unsigned short Xs[64 * 268];   // [n][k256], pitch 268

    const int t = threadIdx.x, lane = t & 63, w = t >> 6;
    const int lj = lane & 15, q = lane >> 4;
    const int n0 = blockIdx.x * 64;
    const int mi = blockIdx.y;
    const float* xp = x + (size_t)mi * SLICE;

    // stage + transpose + cvt (c-pairs -> packed u32 LDS writes)
#pragma unroll
    for (int r = 0; r < 8; ++r) {
        int job = t + r * 256;          // 0..2047
        int cp = job >> 4;              // c-pair 0..127
        int seg = job & 15;             // 4-wide n segment
        float4 va = *(const float4*)(xp + (size_t)(2 * cp) * NPIX + n0 + seg * 4);
        float4 vb = *(const float4*)(xp + (size_t)(2 * cp + 1) * NPIX + n0 + seg * 4);
        u16x4 da = cvt4(va.x, va.y, va.z, va.w);
        u16x4 db = cvt4(vb.x, vb.y, vb.z, vb.w);
#pragma unroll
        for (int e = 0; e < 4; ++e) {
            unsigned pk = (unsigned)da[e] | ((unsigned)db[e] << 16);
            *(unsigned*)&Xs[(seg * 4 + e) * 268 + 2 * cp] = pk;
        }
    }
    __syncthreads();

    f32x4 acc[5][4];
#pragma unroll
    for (int i = 0; i < 5; ++i)
#pragma unroll
        for (int b = 0; b < 4; ++b) acc[i][b] = (f32x4){0.f, 0.f, 0.f, 0.f};

    const unsigned short* wbase = Wb + (size_t)(w * 16 + lj) * CCH + q * 8;
    const unsigned short* xbase = &Xs[lj * 268 + q * 8];

#pragma unroll 2
    for (int kc = 0; kc < CCH; kc += 32) {
        bf16x8 a[5];
#pragma unroll
        for (int i = 0; i < 5; ++i)
            a[i] = ldfrag(wbase + (size_t)i * 64 * CCH + kc);
        bf16x8 xb[4];
#pragma unroll
        for (int b = 0; b < 4; ++b)
            xb[b] = ldfrag(xbase + b * 16 * 268 + kc);
#pragma unroll
        for (int i = 0; i < 5; ++i)
#pragma unroll
            for (int b = 0; b < 4; ++b)
                acc[i][b] = __builtin_amdgcn_mfma_f32_16x16x32_bf16(a[i], xb[b], acc[i][b], 0, 0, 0);
    }

#pragma unroll
    for (int i = 0; i < 5; ++i) {
        const int o16 = (w + 4 * i) * 16;
        const int ob = o16 + 4 * q;
        if (o16 < 32) {                    // Q -> Qt[n][o], pre-scaled by log2(e)
            unsigned short* Qp = Qt + (size_t)mi * NPIX * QCH;
            float b0 = bq[ob], b1 = bq[ob + 1], b2 = bq[ob + 2], b3 = bq[ob + 3];
#pragma unroll
            for (int b = 0; b < 4; ++b) {
                int n = n0 + b * 16 + lj;
                *(u16x4*)(Qp + (size_t)n * QCH + ob) =
                    cvt4((acc[i][b][0] + b0) * L2E, (acc[i][b][1] + b1) * L2E,
                         (acc[i][b][2] + b2) * L2E, (acc[i][b][3] + b3) * L2E);
            }
        } else if (o16 < 64) {             // K -> Kt[n][o]
            unsigned short* Kp = Kt + (size_t)mi * NPIX * QCH;
            int o2 = ob - 32;
            float b0 = bk[o2], b1 = bk[o2 + 1], b2 = bk[o2 + 2], b3 = bk[o2 + 3];
#pragma unroll
            for (int b = 0; b < 4; ++b) {
                int n = n0 + b * 16 + lj;
                *(u16x4*)(Kp + (size_t)n * QCH + o2) =
                    cvt4(acc[i][b][0] + b0, acc[i][b][1] + b1,
                         acc[i][b][2] + b2, acc[i][b][3] + b3);
            }
        } else {                           // V -> A-fragment layout (verified r3-r5)
            unsigned short* Vw = V + (size_t)mi * SLICE;
            const int c16 = (o16 - 64) >> 4;
            const int n05 = n0 >> 5;
            const int cb = (o16 - 64) + 4 * q;
            float bb[4] = { bv[cb], bv[cb + 1], bv[cb + 2], bv[cb + 3] };
            const int ni = lj & 7;
#pragma unroll
            for (int b = 0; b < 4; ++b) {
                int n5 = n05 + (b >> 1);
                int fl = ((2 * b + (lj >> 3)) & 3) * 16 + 4 * q;
                size_t base = ((size_t)(c16 * 32 + n5) * 64 + fl) * 8 + ni;
#pragma unroll
                for (int r = 0; r < 4; ++r)
                    Vw[base + (size_t)r * 8] = f2bf(acc[i][b][r] + bb[r]);
            }
        }
    }
}

// ---------------------------------------------------------------------------
// K2 (primary): compute E once, materialize Pu = exp2(e-SHIFT) as bf16
// B-frags; accumulate row sums S in fp32; then RMW-scale V frags by 1/S
// (normalization folded into V -> K3 becomes a pure GEMM).
// Block = n128 (4 waves x n32), grid (8, MB).
// ---------------------------------------------------------------------------
__global__ __launch_bounds__(256) void k_stats_pu(
    const unsigned short* __restrict__ Qt, const unsigned short* __restrict__ Kt,
    unsigned short* __restrict__ V, unsigned short* __restrict__ Pu)
{
    __shared__ unsigned short Ps[4][32][36];   // wave-private [j32][n32], pitch 36
    __shared__ float rs[128];                  // 1/S per row

    const int t = threadIdx.x, lane = t & 63, w = t >> 6;
    const int lj = lane & 15, q = lane >> 4;
    const int n0b = blockIdx.x * 128;
    const int nw = n0b + w * 32;
    const int mi = blockIdx.y;
    const unsigned short* Qp = Qt + (size_t)mi * NPIX * QCH;
    const unsigned short* Kp = Kt + (size_t)mi * NPIX * QCH;
    unsigned short* Pup = Pu + (size_t)mi * NPIX * NPIX;

    bf16x8 qa[2];
#pragma unroll
    for (int h = 0; h < 2; ++h)
        qa[h] = ldfrag(Qp + (size_t)(nw + h * 16 + lj) * QCH + q * 8);

    float s[2][4];
#pragma unroll
    for (int h = 0; h < 2; ++h)
#pragma unroll
        for (int r = 0; r < 4; ++r) s[h][r] = 0.f;

#pragma unroll 2
    for (int jc = 0; jc < NPIX; jc += 32) {
#pragma unroll
        for (int f = 0; f < 2; ++f) {
            bf16x8 kb = ldfrag(Kp + (size_t)(jc + f * 16 + lj) * QCH + q * 8);
#pragma unroll
            for (int h = 0; h < 2; ++h) {
                f32x4 z = (f32x4){0.f, 0.f, 0.f, 0.f};
                f32x4 e = __builtin_amdgcn_mfma_f32_16x16x32_bf16(qa[h], kb, z, 0, 0, 0);
                float p0 = exp2f(e[0] - SHIFT), p1 = exp2f(e[1] - SHIFT);
                float p2 = exp2f(e[2] - SHIFT), p3 = exp2f(e[3] - SHIFT);
                s[h][0] += p0; s[h][1] += p1; s[h][2] += p2; s[h][3] += p3;
                *(u16x4*)&Ps[w][f * 16 + lj][h * 16 + 4 * q] = cvt4(p0, p1, p2, p3);
            }
        }
        // read back as B-frags (k=n32 x j16) and store to global frag layout
#pragma unroll
        for (int f = 0; f < 2; ++f) {
            u32x4 bfrag = *(const u32x4*)&Ps[w][f * 16 + lj][q * 8];
            *(u32x4*)(Pup + ((size_t)((jc >> 4) + f) * 32 + (nw >> 5)) * 512 + lane * 8) = bfrag;
        }
    }

#pragma unroll
    for (int msk = 1; msk <= 8; msk <<= 1)
#pragma unroll
        for (int h = 0; h < 2; ++h)
#pragma unroll
            for (int r = 0; r < 4; ++r) s[h][r] += __shfl_xor(s[h][r], msk, 64);
    if (lj == 0) {
#pragma unroll
        for (int h = 0; h < 2; ++h)
#pragma unroll
            for (int r = 0; r < 4; ++r)
                rs[w * 32 + h * 16 + 4 * q + r] = 1.0f / s[h][r];
    }
    __syncthreads();

    // scale V frags (all c16, this block's 4 n5 windows) by 1/S_n
    unsigned short* Vp = V + (size_t)mi * SLICE;
    const int n5b = n0b >> 5;
#pragma unroll
    for (int r = 0; r < 16; ++r) {
        int job = t + r * 256;          // 0..4095
        int fr = job >> 6, ln = job & 63;
        size_t base = ((size_t)((fr >> 2) * 32 + n5b + (fr & 3)) * 64 + ln) * 8;
        u16x4 lo = *(const u16x4*)(Vp + base);
        u16x4 hi = *(const u16x4*)(Vp + base + 4);
        const float* rp = &rs[(fr & 3) * 32 + (ln >> 4) * 8];   // n_loc = (ln>>4)*8+i
        u16x4 nlo = cvt4(bf2f(lo[0]) * rp[0], bf2f(lo[1]) * rp[1],
                         bf2f(lo[2]) * rp[2], bf2f(lo[3]) * rp[3]);
        u16x4 nhi = cvt4(bf2f(hi[0]) * rp[4], bf2f(hi[1]) * rp[5],
                         bf2f(hi[2]) * rp[6], bf2f(hi[3]) * rp[7]);
        *(u16x4*)(Vp + base) = nlo;
        *(u16x4*)(Vp + base + 4) = nhi;
    }
}

// ---------------------------------------------------------------------------
// K3 (primary): pure fragment GEMM O = V' @ Pu + residual. No exp2, no
// transpose. V dbuf LDS (one barrier/chunk), Pu B-frags prefetched from
// global. XCD swizzle as r5 (verified: FETCH 92->27MB).
// ---------------------------------------------------------------------------
__global__ __launch_bounds__(256) void k_gemm_out(
    const float* __restrict__ x, const float* __restrict__ gamma,
    const unsigned short* __restrict__ Vf, const unsigned short* __restrict__ Pu,
    float* __restrict__ out)
{
    __shared__ unsigned short Vs[2][8 * 512];   // dbuf: 8 c-frags x 1KB

    const int b = blockIdx.x;
    const int mi  = (b & 7) | ((b >> 7) << 3);
    const int sub = (b >> 3) & 15;
    const int j0  = (sub & 7) * 128;
    const int cb  = sub >> 3;

    const int t = threadIdx.x, lane = t & 63, w = t >> 6;
    const int lj = lane & 15, q = lane >> 4;
    const int jw = j0 + w * 32;

    const unsigned short* Vp  = Vf + (size_t)mi * SLICE;
    const unsigned short* Pup = Pu + (size_t)mi * NPIX * NPIX
                              + ((size_t)(jw >> 4) * 32) * 512 + lane * 8;

    const int ctl = t >> 5, ln0 = (t & 31) * 2;
    const unsigned short* vsrc0 = Vp + ((size_t)(cb * 8 + ctl) * 32) * 512 + ln0 * 8;

    f32x4 acc[8][2];
#pragma unroll
    for (int ci = 0; ci < 8; ++ci)
#pragma unroll
        for (int f = 0; f < 2; ++f) acc[ci][f] = (f32x4){0.f, 0.f, 0.f, 0.f};

    // prestage chunk 0
    {
        u32x4 d0 = *(const u32x4*)vsrc0;
        u32x4 d1 = *(const u32x4*)(vsrc0 + 8);
        *(u32x4*)&Vs[0][ctl * 512 + ln0 * 8] = d0;
        *(u32x4*)&Vs[0][ctl * 512 + ln0 * 8 + 8] = d1;
    }
    bf16x8 pf[2];
#pragma unroll
    for (int f = 0; f < 2; ++f) pf[f] = ldfrag(Pup + f * 16384);
    __syncthreads();

    int p = 0;
    for (int nc = 0; nc < NPIX; nc += 32, p ^= 1) {
        const int nn = (nc + 32) & (NPIX - 1);
        // prefetch next V + Pu
        const unsigned short* vsrc = vsrc0 + (size_t)(nn >> 5) * 512;
        u32x4 nv0 = *(const u32x4*)vsrc;
        u32x4 nv1 = *(const u32x4*)(vsrc + 8);
        bf16x8 pf_n[2];
#pragma unroll
        for (int f = 0; f < 2; ++f)
            pf_n[f] = ldfrag(Pup + f * 16384 + (size_t)(nn >> 5) * 512);

        // O phase: 16 MFMA
#pragma unroll
        for (int ci = 0; ci < 8; ++ci) {
            bf16x8 vfr = ldfrag(&Vs[p][ci * 512 + lane * 8]);
#pragma unroll
            for (int f = 0; f < 2; ++f)
                acc[ci][f] = __builtin_amdgcn_mfma_f32_16x16x32_bf16(vfr, pf[f], acc[ci][f], 0, 0, 0);
        }

        *(u32x4*)&Vs[p ^ 1][ctl * 512 + ln0 * 8] = nv0;
        *(u32x4*)&Vs[p ^ 1][ctl * 512 + ln0 * 8 + 8] = nv1;
        __syncthreads();
        pf[0] = pf_n[0]; pf[1] = pf_n[1];
    }

    const float g = gamma[0];
    const size_t obase = (size_t)mi * SLICE;
#pragma unroll
    for (int ci = 0; ci < 8; ++ci) {
#pragma unroll
        for (int f = 0; f < 2; ++f) {
#pragma unroll
            for (int r = 0; r < 4; ++r) {
                int c = cb * 128 + ci * 16 + 4 * q + r;
                int j = jw + f * 16 + lj;
                size_t off = obase + (size_t)c * NPIX + j;
                out[off] = g * acc[ci][f][r] + x[off];
            }
        }
    }
}

// ---------------------------------------------------------------------------
// Fallback K2/K3 (r5-verified) for small ws_size.
// ---------------------------------------------------------------------------
__global__ __launch_bounds__(256) void k_stats(
    const unsigned short* __restrict__ Qt, const unsigned short* __restrict__ Kt,
    float* __restrict__ a2f)
{
    const int t = threadIdx.x, lane = t & 63, w = t >> 6;
    const int lj = lane & 15, q = lane >> 4;
    const int n16 = blockIdx.x * 64 + w * 16;
    const int mi = blockIdx.y;
    const unsigned short* Qp = Qt + (size_t)mi * NPIX * QCH;
    const unsigned short* Kp = Kt + (size_t)mi * NPIX * QCH;

    bf16x8 qa = ldfrag(Qp + (size_t)(n16 + lj) * QCH + q * 8);

    float s[4] = { 0.f, 0.f, 0.f, 0.f };
#pragma unroll 8
    for (int jc = 0; jc < NPIX; jc += 16) {
        bf16x8 kb = ldfrag(Kp + (size_t)(jc + lj) * QCH + q * 8);
        f32x4 z = (f32x4){0.f, 0.f, 0.f, 0.f};
        f32x4 e = __builtin_amdgcn_mfma_f32_16x16x32_bf16(qa, kb, z, 0, 0, 0);
#pragma unroll
        for (int r = 0; r < 4; ++r) s[r] += exp2f(e[r] - SHIFT);
    }
#pragma unroll
    for (int msk = 1; msk <= 8; msk <<= 1)
#pragma unroll
        for (int r = 0; r < 4; ++r) s[r] += __shfl_xor(s[r], msk, 64);
    if (lj == 0) {
        float* apo = a2f + (size_t)mi * NPIX;
#pragma unroll
        for (int r = 0; r < 4; ++r)
            apo[n16 + 4 * q + r] = SHIFT + log2f(s[r]);
    }
}

__global__ __launch_bounds__(256) void k_attn_out(
    const float* __restrict__ x, const float* __restrict__ gamma,
    const unsigned short* __restrict__ Qt, const unsigned short* __restrict__ Kt,
    const unsigned short* __restrict__ Vf, const float* __restrict__ a2f,
    float* __restrict__ out)
{
    __shared__ unsigned short Vs[2][8 * 512];
    __shared__ unsigned short Ps[4][32][36];

    const int b = blockIdx.x;
    const int mi  = (b & 7) | ((b >> 7) << 3);
    const int sub = (b >> 3) & 15;
    const int j0  = (sub & 7) * 128;
    const int cb  = sub >> 3;

    const int t = threadIdx.x, lane = t & 63, w = t >> 6;
    const int lj = lane & 15, q = lane >> 4;
    const int jw = j0 + w * 32;

    const unsigned short* Qp = Qt + (size_t)mi * NPIX * QCH;
    const unsigned short* Kp = Kt + (size_t)mi * NPIX * QCH;
    const unsigned short* Vp = Vf + (size_t)mi * SLICE;
    const float* ap = a2f + (size_t)mi * NPIX;

    bf16x8 kb[2];
#pragma unroll
    for (int sj = 0; sj < 2; ++sj)
        kb[sj] = ldfrag(Kp + (size_t)(jw + sj * 16 + lj) * QCH + q * 8);

    const int ctl = t >> 5, ln0 = (t & 31) * 2;
    const unsigned short* vsrc0 = Vp + ((size_t)(cb * 8 + ctl) * 32) * 512 + ln0 * 8;

    f32x4 acc[8][2];
#pragma unroll
    for (int ci = 0; ci < 8; ++ci)
#pragma unroll
        for (int ji = 0; ji < 2; ++ji) acc[ci][ji] = (f32x4){0.f, 0.f, 0.f, 0.f};

    {
        u32x4 d0 = *(const u32x4*)vsrc0;
        u32x4 d1 = *(const u32x4*)(vsrc0 + 8);
        *(u32x4*)&Vs[0][ctl * 512 + ln0 * 8] = d0;
        *(u32x4*)&Vs[0][ctl * 512 + ln0 * 8 + 8] = d1;
    }
    bf16x8 qa_n[2];
    f32x4  a4_n[2];
#pragma unroll
    for (int sn = 0; sn < 2; ++sn) {
        qa_n[sn] = ldfrag(Qp + (size_t)(sn * 16 + lj) * QCH + q * 8);
        a4_n[sn] = *(const f32x4*)(ap + sn * 16 + 4 * q);
    }
    __syncthreads();

    int p = 0;
    for (int nc = 0; nc < NPIX; nc += 32, p ^= 1) {
        const int nn = (nc + 32) & (NPIX - 1);
        const unsigned short* vsrc = vsrc0 + (size_t)(nn >> 5) * 512;
        u32x4 nv0 = *(const u32x4*)vsrc;
        u32x4 nv1 = *(const u32x4*)(vsrc + 8);

        bf16x8 qa0 = qa_n[0], qa1 = qa_n[1];
        f32x4 a40 = a4_n[0], a41 = a4_n[1];
#pragma unroll
        for (int sj = 0; sj < 2; ++sj) {
            f32x4 z = (f32x4){0.f, 0.f, 0.f, 0.f};
            f32x4 e0 = __builtin_amdgcn_mfma_f32_16x16x32_bf16(qa0, kb[sj], z, 0, 0, 0);
            f32x4 e1 = __builtin_amdgcn_mfma_f32_16x16x32_bf16(qa1, kb[sj], z, 0, 0, 0);
            *(u16x4*)&Ps[w][sj * 16 + lj][4 * q] =
                cvt4(exp2f(e0[0] - a40[0]), exp2f(e0[1] - a40[1]),
                     exp2f(e0[2] - a40[2]), exp2f(e0[3] - a40[3]));
            *(u16x4*)&Ps[w][sj * 16 + lj][16 + 4 * q] =
                cvt4(exp2f(e1[0] - a41[0]), exp2f(e1[1] - a41[1]),
                     exp2f(e1[2] - a41[2]), exp2f(e1[3] - a41[3]));
        }
#pragma unroll
        for (int sn = 0; sn < 2; ++sn) {
            qa_n[sn] = ldfrag(Qp + (size_t)(nn + sn * 16 + lj) * QCH + q * 8);
            a4_n[sn] = *(const f32x4*)(ap + nn + sn * 16 + 4 * q);
        }

        bf16x8 pf[2];
#pragma unroll
        for (int ji = 0; ji < 2; ++ji)
            pf[ji] = ldfrag(&Ps[w][ji * 16 + lj][q * 8]);
#pragma unroll
        for (int ci = 0; ci < 8; ++ci) {
            bf16x8 vfr = ldfrag(&Vs[p][ci * 512 + lane * 8]);
#pragma unroll
            for (int ji = 0; ji < 2; ++ji)
                acc[ci][ji] = __builtin_amdgcn_mfma_f32_16x16x32_bf16(vfr, pf[ji], acc[ci][ji], 0, 0, 0);
        }

        *(u32x4*)&Vs[p ^ 1][ctl * 512 + ln0 * 8] = nv0;
        *(u32x4*)&Vs[p ^ 1][ctl * 512 + ln0 * 8 + 8] = nv1;
        __syncthreads();
    }

    const float g = gamma[0];
    const size_t obase = (size_t)mi * SLICE;
#pragma unroll
    for (int ci = 0; ci < 8; ++ci) {
#pragma unroll
        for (int ji = 0; ji < 2; ++ji) {
#pragma unroll
            for (int r = 0; r < 4; ++r) {
                int c = cb * 128 + ci * 16 + 4 * q + r;
                int j = jw + ji * 16 + lj;
                size_t off = obase + (size_t)c * NPIX + j;
                out[off] = g * acc[ci][ji][r] + x[off];
            }
        }
    }
}

extern "C" void kernel_launch(void* const* d_in, const int* in_sizes, int n_in,
                              void* d_out, int out_size, void* d_ws, size_t ws_size,
                              hipStream_t stream)
{
    const float* x     = (const float*)d_in[0];
    const float* wq    = (const float*)d_in[1];
    const float* bq    = (const float*)d_in[2];
    const float* wk    = (const float*)d_in[3];
    const float* bk    = (const float*)d_in[4];
    const float* wv    = (const float*)d_in[5];
    const float* bv    = (const float*)d_in[6];
    const float* gamma = (const float*)d_in[7];
    float* out = (float*)d_out;

    char* wsb = (char*)d_ws;
    unsigned short* Wb = (unsigned short*)(wsb + WB_OFF);
    unsigned short* Qt = (unsigned short*)(wsb + QT_OFF);
    unsigned short* Kt = (unsigned short*)(wsb + KT_OFF);
    unsigned short* V  = (unsigned short*)(wsb + V_OFF);
    float*          a2 = (float*)(wsb + A2F_OFF);
    unsigned short* Pu = (unsigned short*)(wsb + PU_OFF);

    k_prep_w<<<80, 256, 0, stream>>>(wq, wk, wv, Wb);
    k_proj<<<dim3(NPIX / 64, MB), 256, 0, stream>>>(x, Wb, bq, bk, bv, Qt, Kt, V);

    if (ws_size >= (size_t)WS_NEED) {
        k_stats_pu<<<dim3(NPIX / 128, MB), 256, 0, stream>>>(Qt, Kt, V, Pu);
        k_gemm_out<<<512, 256, 0, stream>>>(x, gamma, V, Pu, out);
    } else {
        k_stats<<<dim3(NPIX / 64, MB), 256, 0, stream>>>(Qt, Kt, a2);
        k_attn_out<<<512, 256, 0, stream>>>(x, gamma, Qt, Kt, V, a2, out);
    }
}